// Round 8
// baseline (213.625 us; speedup 1.0000x reference)
//
#include <hip/hip_runtime.h>
#include <hip/hip_bf16.h>

typedef __bf16 bf16_t;
typedef bf16_t bf16x8 __attribute__((ext_vector_type(8)));
typedef float f32x4 __attribute__((ext_vector_type(4)));
typedef unsigned short u16;
typedef unsigned int u32;

static __device__ __forceinline__ u16 f2bf(float f) {
    __hip_bfloat16 h = __float2bfloat16(f);
    return __builtin_bit_cast(u16, h);
}
// float -> __bf16 with RNE via bit-cast (NOT integer conversion!)
static __device__ __forceinline__ bf16_t fb(float f) {
    return __builtin_bit_cast(bf16_t, f2bf(f));
}
static __device__ __forceinline__ float bf2f(u16 u) {
    u32 x = ((u32)u) << 16;
    return __builtin_bit_cast(float, x);
}
static __device__ __forceinline__ float softthr(float v, float l) {
    return copysignf(fmaxf(fabsf(v) - l, 0.0f), v);
}

// trivial: Dict copy to out[2]
__global__ __launch_bounds__(256) void copy_dict(const float* __restrict__ Dict,
                                                 float* __restrict__ outd)
{
    int i = blockIdx.x * 256 + threadIdx.x;   // 65536 total
    outd[i] = Dict[i];
}

// ---- fused LISTA, rank-128 factored, dict-in-registers, split-K G1 ----
// z_{t+1} = ST( z_t + (x - z_t @ D^T) @ D / L ),  z_0 = ST(x @ D)
// G1 split-K: wave (dg,ag) computes partial[dg's 64 dims][32 px] over
//   ag's 128 atoms, from its private -D slice (regs) and an 8KB zl slice.
//   Partials (bf16) are reduced (4-way) + x, scaled 1/L -> rl.
// G2: accz[atom][px] += D^T @ r^T  (K=128) — accz fp32 regs IS z.
// Recon: x_recon = -(sum of final partials).
__global__ __launch_bounds__(512, 2)
void lista_main(const float* __restrict__ x,
                const float* __restrict__ Dict,    // fp32 [128][512]
                const float* __restrict__ alpha,
                const float* __restrict__ Lp,
                const int* __restrict__ nip,
                float* __restrict__ outz,          // [32][512][1024]
                float* __restrict__ outr)          // [32][128][1024]
{
    __shared__ __align__(16) u16 zl[32 * 512];       // 32 KB z bf16 [px][atom]
    __shared__ __align__(16) u16 rl[32 * 128];       // 8 KB r bf16 [px][dim]
    __shared__ __align__(16) u16 xs[32 * 128];       // 8 KB x bf16 [px][dim]
    __shared__ __align__(16) u16 pb[32 * 4 * 128];   // 32 KB partials bf16 [px][ag][dim]

    const int t = threadIdx.x;
    const int lane = t & 63;
    const int l15 = lane & 15;
    const int lg = lane >> 4;            // 0..3
    const int wave = t >> 6;             // 0..7
    const int dg = wave >> 2;            // 0..1 : G1 dim-group (64 dims)
    const int ag = wave & 3;             // 0..3 : G1 atom-group (128 atoms)
    const int atb = wave << 6;           // G2 atom base (64 atoms/wave)
    const int bb = blockIdx.x >> 5;             // batch
    const int hw0 = (blockIdx.x & 31) << 5;     // 32-pixel base
    const float invL = 1.0f / Lp[0];
    const int niter = nip[0];

    // reduce-pass mapping: thread -> (pixel, dim-octet)
    const int rpx = t & 31;
    const int roc = t >> 5;              // 0..15

    // ---- stage xs = bf16(x) [px][dim] swizzled ----
    for (int i = t; i < 32 * 128; i += 512) {
        int d = i >> 5, px = i & 31;
        xs[((px << 7) + d) ^ ((px & 7) << 3)] =
            f2bf(x[((bb * 128 + d) << 10) + hw0 + px]);
    }

    // thresholds at G2 C columns (px)
    float thr[2];
#pragma unroll
    for (int nt = 0; nt < 2; ++nt)
        thr[nt] = alpha[hw0 + nt * 16 + l15] * invL;

    // ---- dict fragments -> registers (once) ----
    // G1 A: -D[dg*64+mt*16+l15][ag*128+kt*32+lg*8+j]  (row-contiguous)
    bf16x8 g1a[4][4];
#pragma unroll
    for (int mt = 0; mt < 4; ++mt) {
        const float* drow = Dict + ((dg * 64 + mt * 16 + l15) << 9) + ag * 128 + lg * 8;
#pragma unroll
        for (int kt = 0; kt < 4; ++kt) {
            f32x4 c0 = *reinterpret_cast<const f32x4*>(drow + kt * 32);
            f32x4 c1 = *reinterpret_cast<const f32x4*>(drow + kt * 32 + 4);
#pragma unroll
            for (int j = 0; j < 4; ++j) {
                g1a[mt][kt][j] = fb(-c0[j]);
                g1a[mt][kt][j + 4] = fb(-c1[j]);
            }
        }
    }
    // G2 A: D^T[atb+at*16+l15][kt*32+lg*8+j] (column gather, once)
    bf16x8 g2a[4][4];
#pragma unroll
    for (int at = 0; at < 4; ++at)
#pragma unroll
        for (int kt = 0; kt < 4; ++kt)
#pragma unroll
            for (int j = 0; j < 8; ++j)
                g2a[at][kt][j] = fb(Dict[((kt * 32 + lg * 8 + j) << 9) + atb + at * 16 + l15]);

    __syncthreads();

    f32x4 accz[4][2];
#pragma unroll
    for (int at = 0; at < 4; ++at)
#pragma unroll
        for (int nt = 0; nt < 2; ++nt)
            accz[at][nt] = f32x4{0.f, 0.f, 0.f, 0.f};

    // G2 + threshold + zl write; B source = [px][dim] swizzled bf16 buffer
    auto run_g2 = [&](const u16* __restrict__ bsrc) {
#pragma unroll
        for (int kt = 0; kt < 4; ++kt) {
            bf16x8 Bf[2];
#pragma unroll
            for (int nt = 0; nt < 2; ++nt) {
                int px = nt * 16 + l15;
                Bf[nt] = *reinterpret_cast<const bf16x8*>(
                    &bsrc[((px << 7) + kt * 32 + lg * 8) ^ ((px & 7) << 3)]);
            }
            __builtin_amdgcn_s_setprio(1);
#pragma unroll
            for (int at = 0; at < 4; ++at)
#pragma unroll
                for (int nt = 0; nt < 2; ++nt)
                    accz[at][nt] = __builtin_amdgcn_mfma_f32_16x16x32_bf16(
                        g2a[at][kt], Bf[nt], accz[at][nt], 0, 0, 0);
            __builtin_amdgcn_s_setprio(0);
        }
#pragma unroll
        for (int at = 0; at < 4; ++at)
#pragma unroll
            for (int nt = 0; nt < 2; ++nt) {
                int px = nt * 16 + l15;
                f32x4 a = accz[at][nt];
                a[0] = softthr(a[0], thr[nt]);
                a[1] = softthr(a[1], thr[nt]);
                a[2] = softthr(a[2], thr[nt]);
                a[3] = softthr(a[3], thr[nt]);
                accz[at][nt] = a;
                uint2 pk;
                pk.x = (u32)f2bf(a[0]) | ((u32)f2bf(a[1]) << 16);
                pk.y = (u32)f2bf(a[2]) | ((u32)f2bf(a[3]) << 16);
                *reinterpret_cast<uint2*>(
                    &zl[((px << 9) + atb + at * 16 + lg * 4) ^ ((px & 7) << 3)]) = pk;
            }
    };

    // G1 split-K: partials over ag's 128 atoms -> pb (bf16)
    auto run_g1 = [&]() {
        f32x4 a1p[4][2];
#pragma unroll
        for (int mt = 0; mt < 4; ++mt)
#pragma unroll
            for (int nt = 0; nt < 2; ++nt)
                a1p[mt][nt] = f32x4{0.f, 0.f, 0.f, 0.f};
#pragma unroll
        for (int kt = 0; kt < 4; ++kt) {
            bf16x8 Bf[2];
#pragma unroll
            for (int nt = 0; nt < 2; ++nt) {
                int px = nt * 16 + l15;
                Bf[nt] = *reinterpret_cast<const bf16x8*>(
                    &zl[((px << 9) + ag * 128 + kt * 32 + lg * 8) ^ ((px & 7) << 3)]);
            }
            __builtin_amdgcn_s_setprio(1);
#pragma unroll
            for (int mt = 0; mt < 4; ++mt)
#pragma unroll
                for (int nt = 0; nt < 2; ++nt)
                    a1p[mt][nt] = __builtin_amdgcn_mfma_f32_16x16x32_bf16(
                        g1a[mt][kt], Bf[nt], a1p[mt][nt], 0, 0, 0);
            __builtin_amdgcn_s_setprio(0);
        }
#pragma unroll
        for (int mt = 0; mt < 4; ++mt)
#pragma unroll
            for (int nt = 0; nt < 2; ++nt) {
                int px = nt * 16 + l15;
                int d0 = dg * 64 + mt * 16 + lg * 4;
                f32x4 a = a1p[mt][nt];
                uint2 pk;
                pk.x = (u32)f2bf(a[0]) | ((u32)f2bf(a[1]) << 16);
                pk.y = (u32)f2bf(a[2]) | ((u32)f2bf(a[3]) << 16);
                *reinterpret_cast<uint2*>(
                    &pb[((px << 9) + (ag << 7) + d0) ^ ((px & 7) << 3)]) = pk;
            }
    };

    // ---- it 0: z0 = ST(x @ D) — G2 with B = xs (unscaled) ----
    run_g2(xs);
    __syncthreads();

    // ---- main loop ----
    for (int it = 1; it <= niter; ++it) {
        run_g1();
        __syncthreads();
        // reduce: r = (x + sum_ag partial) * invL -> rl
        {
            const int sw = (rpx & 7) << 3;
            bf16x8 p0 = *reinterpret_cast<const bf16x8*>(&pb[((rpx << 9) + 0 * 128 + roc * 8) ^ sw]);
            bf16x8 p1 = *reinterpret_cast<const bf16x8*>(&pb[((rpx << 9) + 1 * 128 + roc * 8) ^ sw]);
            bf16x8 p2 = *reinterpret_cast<const bf16x8*>(&pb[((rpx << 9) + 2 * 128 + roc * 8) ^ sw]);
            bf16x8 p3 = *reinterpret_cast<const bf16x8*>(&pb[((rpx << 9) + 3 * 128 + roc * 8) ^ sw]);
            bf16x8 xv = *reinterpret_cast<const bf16x8*>(&xs[((rpx << 7) + roc * 8) ^ sw]);
            bf16x8 rv;
#pragma unroll
            for (int e = 0; e < 8; ++e) {
                float s = ((float)xv[e] + (float)p0[e]) + ((float)p1[e] + (float)p2[e]) + (float)p3[e];
                rv[e] = fb(s * invL);
            }
            *reinterpret_cast<bf16x8*>(&rl[((rpx << 7) + roc * 8) ^ sw]) = rv;
        }
        __syncthreads();
        run_g2(rl);
        __syncthreads();
    }

    // ---- final G1 -> partials; recon = -(sum partials) ----
    run_g1();
    __syncthreads();
    float rec[8];
    {
        const int sw = (rpx & 7) << 3;
        bf16x8 p0 = *reinterpret_cast<const bf16x8*>(&pb[((rpx << 9) + 0 * 128 + roc * 8) ^ sw]);
        bf16x8 p1 = *reinterpret_cast<const bf16x8*>(&pb[((rpx << 9) + 1 * 128 + roc * 8) ^ sw]);
        bf16x8 p2 = *reinterpret_cast<const bf16x8*>(&pb[((rpx << 9) + 2 * 128 + roc * 8) ^ sw]);
        bf16x8 p3 = *reinterpret_cast<const bf16x8*>(&pb[((rpx << 9) + 3 * 128 + roc * 8) ^ sw]);
#pragma unroll
        for (int e = 0; e < 8; ++e)
            rec[e] = -(((float)p0[e] + (float)p1[e]) + ((float)p2[e] + (float)p3[e]));
    }

    // ---- store z from zl (nontemporal, coalesced) ----
    for (int i = t; i < 32 * 512; i += 512) {
        int a = i >> 5, px = i & 31;
        float zv = bf2f(zl[((px << 9) + a) ^ ((px & 7) << 3)]);
        __builtin_nontemporal_store(zv, &outz[((bb * 512 + a) << 10) + hw0 + px]);
    }
    __syncthreads();   // all pb reads done -> safe to overwrite as fp32

    // ---- stage recon fp32 [px][dim] swizzled into pb region ----
    {
        float* wf = reinterpret_cast<float*>(pb);
        const int swf = (rpx & 7) << 2;
        f32x4 lo{rec[0], rec[1], rec[2], rec[3]};
        f32x4 hi{rec[4], rec[5], rec[6], rec[7]};
        *reinterpret_cast<f32x4*>(&wf[((rpx << 7) + roc * 8) ^ swf]) = lo;
        *reinterpret_cast<f32x4*>(&wf[((rpx << 7) + roc * 8 + 4) ^ swf]) = hi;
    }
    __syncthreads();

    // ---- store x_recon (nontemporal, coalesced) ----
    {
        const float* wf = reinterpret_cast<const float*>(pb);
        for (int i = t; i < 32 * 128; i += 512) {
            int d = i >> 5, px = i & 31;
            __builtin_nontemporal_store(wf[((px << 7) + d) ^ ((px & 7) << 2)],
                                        &outr[((bb * 128 + d) << 10) + hw0 + px]);
        }
    }
}

extern "C" void kernel_launch(void* const* d_in, const int* in_sizes, int n_in,
                              void* d_out, int out_size, void* d_ws, size_t ws_size,
                              hipStream_t stream)
{
    const float* x     = (const float*)d_in[0];
    const float* Dict  = (const float*)d_in[1];
    const float* alpha = (const float*)d_in[2];
    const float* Lp    = (const float*)d_in[3];
    const int*   nip   = (const int*)d_in[4];

    float* outz = (float*)d_out;                 // [32,512,32,32]
    float* outr = outz + 32 * 512 * 1024;        // [32,128,32,32]
    float* outd = outr + 32 * 128 * 1024;        // [128,512]

    copy_dict<<<dim3(256), dim3(256), 0, stream>>>(Dict, outd);
    lista_main<<<dim3(1024), dim3(512), 0, stream>>>(x, Dict, alpha, Lp, nip,
                                                     outz, outr);
}

// Round 10
// 209.850 us; speedup vs baseline: 1.0180x; 1.0180x over previous
//
#include <hip/hip_runtime.h>
#include <hip/hip_bf16.h>

typedef __bf16 bf16_t;
typedef bf16_t bf16x8 __attribute__((ext_vector_type(8)));
typedef float f32x4 __attribute__((ext_vector_type(4)));
typedef unsigned short u16;
typedef unsigned int u32;

static __device__ __forceinline__ u16 f2bf(float f) {
    __hip_bfloat16 h = __float2bfloat16(f);
    return __builtin_bit_cast(u16, h);
}
// float -> __bf16 with RNE via bit-cast (NOT integer conversion!)
static __device__ __forceinline__ bf16_t fb(float f) {
    return __builtin_bit_cast(bf16_t, f2bf(f));
}
static __device__ __forceinline__ float bf2f(u16 u) {
    u32 x = ((u32)u) << 16;
    return __builtin_bit_cast(float, x);
}
static __device__ __forceinline__ float softthr(float v, float l) {
    return copysignf(fmaxf(fabsf(v) - l, 0.0f), v);
}

// trivial: Dict copy to out[2]
__global__ __launch_bounds__(256) void copy_dict(const float* __restrict__ Dict,
                                                 float* __restrict__ outd)
{
    int i = blockIdx.x * 256 + threadIdx.x;   // 65536 total
    outd[i] = Dict[i];
}

// ---- fused LISTA: rank-128 factored, dict-in-regs, split-K G1,
//      TWO independent 16-px tiles ping-ponged per block (ILP),
//      persistent fp32 z accumulators (R8 numerics) ----
// z_{t+1} = ST( z_t + (x - z_t @ D^T) @ D / L ),  z_0 = ST(x @ D)
__global__ __launch_bounds__(512, 2)
void lista_main(const float* __restrict__ x,
                const float* __restrict__ Dict,    // fp32 [128][512]
                const float* __restrict__ alpha,
                const float* __restrict__ Lp,
                const int* __restrict__ nip,
                float* __restrict__ outz,          // [32][512][1024]
                float* __restrict__ outr)          // [32][128][1024]
{
    __shared__ __align__(16) u16 zl[2][16 * 512];     // 2x16KB z bf16 [px][atom]
    __shared__ __align__(16) u16 rl[2][16 * 128];     // 2x4KB  r bf16 [px][dim]
    __shared__ __align__(16) u16 xs[2][16 * 128];     // 2x4KB  x bf16 [px][dim]
    __shared__ __align__(16) u16 pb[2][16 * 4 * 128]; // 2x16KB partials [px][ag][dim]

    const int t = threadIdx.x;
    const int lane = t & 63;
    const int l15 = lane & 15;           // px within tile / fragment row
    const int lg = lane >> 4;            // 0..3
    const int wave = t >> 6;             // 0..7
    const int dg = wave >> 2;            // 0..1 : G1 dim-group (64 dims)
    const int ag = wave & 3;             // 0..3 : G1 atom-group (128 atoms)
    const int atb = wave << 6;           // G2 atom base (64 atoms/wave)
    const int bb = blockIdx.x >> 5;             // batch
    const int hw0 = (blockIdx.x & 31) << 5;     // 32-pixel base (2 tiles of 16)
    const float invL = 1.0f / Lp[0];
    const int niter = nip[0];

    // ---- stage xs = bf16(x) [px][dim] swizzled, both tiles ----
    for (int i = t; i < 2 * 16 * 128; i += 512) {
        int tt = i >> 11, j = i & 2047;
        int d = j >> 4, px = j & 15;
        xs[tt][((px << 7) + d) ^ ((px & 7) << 3)] =
            f2bf(x[((bb * 128 + d) << 10) + hw0 + tt * 16 + px]);
    }

    // thresholds at G2 C columns (px = l15), per tile
    const float thrA = alpha[hw0 + l15] * invL;
    const float thrB = alpha[hw0 + 16 + l15] * invL;

    // ---- dict fragments -> registers (once) ----
    // G1 A: -D[dg*64+mt*16+l15][ag*128+kt*32+lg*8+j]  (row-contiguous)
    bf16x8 g1a[4][4];
#pragma unroll
    for (int mt = 0; mt < 4; ++mt) {
        const float* drow = Dict + ((dg * 64 + mt * 16 + l15) << 9) + ag * 128 + lg * 8;
#pragma unroll
        for (int kt = 0; kt < 4; ++kt) {
            f32x4 c0 = *reinterpret_cast<const f32x4*>(drow + kt * 32);
            f32x4 c1 = *reinterpret_cast<const f32x4*>(drow + kt * 32 + 4);
#pragma unroll
            for (int j = 0; j < 4; ++j) {
                g1a[mt][kt][j] = fb(-c0[j]);
                g1a[mt][kt][j + 4] = fb(-c1[j]);
            }
        }
    }
    // G2 A: D^T[atb+at*16+l15][kt*32+lg*8+j] (column gather, once)
    bf16x8 g2a[4][4];
#pragma unroll
    for (int at = 0; at < 4; ++at)
#pragma unroll
        for (int kt = 0; kt < 4; ++kt)
#pragma unroll
            for (int j = 0; j < 8; ++j)
                g2a[at][kt][j] = fb(Dict[((kt * 32 + lg * 8 + j) << 9) + atb + at * 16 + l15]);

    __syncthreads();

    // G2: acc += D^T @ bsrc^T; ST in place; write z bf16 to zlt.
    // acc is the PERSISTENT fp32 z for this tile (16 regs).
    auto g2_tile = [&](f32x4 (&acc)[4], u16* __restrict__ zlt,
                       const u16* __restrict__ bsrc, float thv) {
#pragma unroll
        for (int kt = 0; kt < 4; ++kt) {
            const int px = l15;
            bf16x8 Bf = *reinterpret_cast<const bf16x8*>(
                &bsrc[((px << 7) + kt * 32 + lg * 8) ^ ((px & 7) << 3)]);
            __builtin_amdgcn_s_setprio(1);
#pragma unroll
            for (int at = 0; at < 4; ++at)
                acc[at] = __builtin_amdgcn_mfma_f32_16x16x32_bf16(
                    g2a[at][kt], Bf, acc[at], 0, 0, 0);
            __builtin_amdgcn_s_setprio(0);
        }
#pragma unroll
        for (int at = 0; at < 4; ++at) {
            const int px = l15;
            f32x4 a = acc[at];
            a[0] = softthr(a[0], thv);
            a[1] = softthr(a[1], thv);
            a[2] = softthr(a[2], thv);
            a[3] = softthr(a[3], thv);
            acc[at] = a;
            uint2 pk;
            pk.x = (u32)f2bf(a[0]) | ((u32)f2bf(a[1]) << 16);
            pk.y = (u32)f2bf(a[2]) | ((u32)f2bf(a[3]) << 16);
            *reinterpret_cast<uint2*>(
                &zlt[((px << 9) + atb + at * 16 + lg * 4) ^ ((px & 7) << 3)]) = pk;
        }
    };

    // G1 split-K: partial over ag's 128 atoms -> pbt (bf16)
    auto g1_tile = [&](const u16* __restrict__ zlt, u16* __restrict__ pbt) {
        f32x4 a1p[4];
#pragma unroll
        for (int mt = 0; mt < 4; ++mt)
            a1p[mt] = f32x4{0.f, 0.f, 0.f, 0.f};
#pragma unroll
        for (int kt = 0; kt < 4; ++kt) {
            const int px = l15;
            bf16x8 Bf = *reinterpret_cast<const bf16x8*>(
                &zlt[((px << 9) + ag * 128 + kt * 32 + lg * 8) ^ ((px & 7) << 3)]);
            __builtin_amdgcn_s_setprio(1);
#pragma unroll
            for (int mt = 0; mt < 4; ++mt)
                a1p[mt] = __builtin_amdgcn_mfma_f32_16x16x32_bf16(
                    g1a[mt][kt], Bf, a1p[mt], 0, 0, 0);
            __builtin_amdgcn_s_setprio(0);
        }
#pragma unroll
        for (int mt = 0; mt < 4; ++mt) {
            const int px = l15;
            int d0 = dg * 64 + mt * 16 + lg * 4;
            f32x4 a = a1p[mt];
            uint2 pk;
            pk.x = (u32)f2bf(a[0]) | ((u32)f2bf(a[1]) << 16);
            pk.y = (u32)f2bf(a[2]) | ((u32)f2bf(a[3]) << 16);
            *reinterpret_cast<uint2*>(
                &pbt[((px << 9) + (ag << 7) + d0) ^ ((px & 7) << 3)]) = pk;
        }
    };

    // reduce both tiles: r = (x + sum_ag partial) * invL -> rl
    auto reduce_all = [&]() {
        const int tt = t >> 8;
        const int px = (t >> 4) & 15;
        const int roc = t & 15;
        const u16* pbt = &pb[0][0] + (tt << 13);
        const u16* xst = &xs[0][0] + (tt << 11);
        u16* rlt = &rl[0][0] + (tt << 11);
        const int sw = (px & 7) << 3;
        bf16x8 p0 = *reinterpret_cast<const bf16x8*>(&pbt[((px << 9) + 0 * 128 + roc * 8) ^ sw]);
        bf16x8 p1 = *reinterpret_cast<const bf16x8*>(&pbt[((px << 9) + 1 * 128 + roc * 8) ^ sw]);
        bf16x8 p2 = *reinterpret_cast<const bf16x8*>(&pbt[((px << 9) + 2 * 128 + roc * 8) ^ sw]);
        bf16x8 p3 = *reinterpret_cast<const bf16x8*>(&pbt[((px << 9) + 3 * 128 + roc * 8) ^ sw]);
        bf16x8 xv = *reinterpret_cast<const bf16x8*>(&xst[((px << 7) + roc * 8) ^ sw]);
        bf16x8 rv;
#pragma unroll
        for (int e = 0; e < 8; ++e) {
            float s = ((float)xv[e] + (float)p0[e]) + ((float)p1[e] + (float)p2[e]) + (float)p3[e];
            rv[e] = fb(s * invL);
        }
        *reinterpret_cast<bf16x8*>(&rlt[((px << 7) + roc * 8) ^ sw]) = rv;
    };

    f32x4 acczA[4], acczB[4];
#pragma unroll
    for (int at = 0; at < 4; ++at) {
        acczA[at] = f32x4{0.f, 0.f, 0.f, 0.f};
        acczB[at] = f32x4{0.f, 0.f, 0.f, 0.f};
    }

    // ---- it 0: z0 = ST(0 + x @ D), both tiles ----
    g2_tile(acczA, zl[0], xs[0], thrA);
    g2_tile(acczB, zl[1], xs[1], thrB);
    __syncthreads();

    // ---- main loop ----
    for (int it = 1; it <= niter; ++it) {
        g1_tile(zl[0], pb[0]);
        g1_tile(zl[1], pb[1]);
        __syncthreads();
        reduce_all();
        __syncthreads();
        g2_tile(acczA, zl[0], rl[0], thrA);
        g2_tile(acczB, zl[1], rl[1], thrB);
        __syncthreads();
    }

    // ---- final G1 -> partials; recon = -(sum partials) ----
    g1_tile(zl[0], pb[0]);
    g1_tile(zl[1], pb[1]);
    __syncthreads();

    float rec[8];
    {
        const int tt = t >> 8;
        const int px = (t >> 4) & 15;
        const int roc = t & 15;
        const u16* pbt = &pb[0][0] + (tt << 13);
        const int sw = (px & 7) << 3;
        bf16x8 p0 = *reinterpret_cast<const bf16x8*>(&pbt[((px << 9) + 0 * 128 + roc * 8) ^ sw]);
        bf16x8 p1 = *reinterpret_cast<const bf16x8*>(&pbt[((px << 9) + 1 * 128 + roc * 8) ^ sw]);
        bf16x8 p2 = *reinterpret_cast<const bf16x8*>(&pbt[((px << 9) + 2 * 128 + roc * 8) ^ sw]);
        bf16x8 p3 = *reinterpret_cast<const bf16x8*>(&pbt[((px << 9) + 3 * 128 + roc * 8) ^ sw]);
#pragma unroll
        for (int e = 0; e < 8; ++e)
            rec[e] = -(((float)p0[e] + (float)p1[e]) + ((float)p2[e] + (float)p3[e]));
    }

    // ---- store z from zl (nontemporal) ----
    for (int i = t; i < 2 * 16 * 512; i += 512) {
        int tt = i >> 13, j = i & 8191;
        int a = j >> 4, px = j & 15;
        float zv = bf2f(zl[tt][((px << 9) + a) ^ ((px & 7) << 3)]);
        __builtin_nontemporal_store(zv, &outz[((bb * 512 + a) << 10) + hw0 + tt * 16 + px]);
    }
    __syncthreads();   // rec already read from pb; safe to overwrite

    // ---- stage recon fp32 [px][dim] swizzled into pb region ----
    {
        const int tt = t >> 8;
        const int px = (t >> 4) & 15;
        const int roc = t & 15;
        float* wf = reinterpret_cast<float*>(&pb[0][0]) + (tt << 12);
        const int swf = (px & 7) << 2;
#pragma unroll
        for (int e = 0; e < 8; ++e)
            wf[((px << 7) + roc * 8 + e) ^ swf] = rec[e];
    }
    __syncthreads();

    // ---- store x_recon (nontemporal) ----
    for (int i = t; i < 2 * 16 * 128; i += 512) {
        int tt = i >> 11, j = i & 2047;
        int d = j >> 4, px = j & 15;
        const float* wf = reinterpret_cast<const float*>(&pb[0][0]) + (tt << 12);
        __builtin_nontemporal_store(wf[((px << 7) + d) ^ ((px & 7) << 2)],
                                    &outr[((bb * 128 + d) << 10) + hw0 + tt * 16 + px]);
    }
}

extern "C" void kernel_launch(void* const* d_in, const int* in_sizes, int n_in,
                              void* d_out, int out_size, void* d_ws, size_t ws_size,
                              hipStream_t stream)
{
    const float* x     = (const float*)d_in[0];
    const float* Dict  = (const float*)d_in[1];
    const float* alpha = (const float*)d_in[2];
    const float* Lp    = (const float*)d_in[3];
    const int*   nip   = (const int*)d_in[4];

    float* outz = (float*)d_out;                 // [32,512,32,32]
    float* outr = outz + 32 * 512 * 1024;        // [32,128,32,32]
    float* outd = outr + 32 * 128 * 1024;        // [128,512]

    copy_dict<<<dim3(256), dim3(256), 0, stream>>>(Dict, outd);
    lista_main<<<dim3(1024), dim3(512), 0, stream>>>(x, Dict, alpha, Lp, nip,
                                                     outz, outr);
}